// Round 1
// 758.826 us; speedup vs baseline: 1.0247x; 1.0247x over previous
//
#include <hip/hip_runtime.h>
#include <hip/hip_bf16.h>
#include <math.h>

typedef __attribute__((ext_vector_type(8))) short   short8;
typedef __attribute__((ext_vector_type(4))) float   floatx4;

// ---------------- workspace layout (bytes) ----------------
#define OFF_PRED     0ULL          // 32*18*4 = 2304
#define OFF_PTA      16384ULL      // 32*96*2*4 = 24576
#define OFF_PTB      65536ULL      // 24576
#define OFF_W2T      131072ULL     // 3 * 524288
#define OFF_F1       2097152ULL    // max 1024*1024*2 = 2 MB
#define OFF_P2       4194304ULL    // 8*1024*256*4 = 8 MB
#define OFF_X        16777216ULL   // 12845056 B
#define OFF_P1       33554432ULL   // 28*256*1024*4 = 29360128 B
#define OFF_W1T      67108864ULL   // 89915392 B total (3 levels)

// ---------------- pair-gather helper (pred point from prev-level pt) ----------
__device__ inline void pair_idx(int p, int Pn, int npnt, int& i1, int& i2) {
    if (p == 0) { i1 = i2 = 0; }
    else if (p >= Pn - 2) { i1 = i2 = npnt - (Pn - p); }
    else {
        int q = (p - 1) >> 1, r = (p - 1) & 1;
        int si = 1 + 3 * q;
        if (r == 0) { i1 = i2 = si; } else { i1 = si + 1; i2 = si + 2; }
    }
}
// nsegP==0 -> read pred0 (B,9,2). else compute pair-mean from pt (B, 3*nsegP, 2)
__device__ inline float2 pred_point(const float* pred0, const float* pt,
                                    int nsegP, int b, int p) {
    if (nsegP == 0) {
        const float* q = pred0 + ((size_t)b * 9 + p) * 2;
        return float2{q[0], q[1]};
    }
    int npnt = nsegP * 3, Pn = 2 * nsegP + 1;
    int i1, i2; pair_idx(p, Pn, npnt, i1, i2);
    const float* a = pt + ((size_t)b * npnt + i1) * 2;
    const float* c = pt + ((size_t)b * npnt + i2) * 2;
    return float2{0.5f * (a[0] + c[0]), 0.5f * (a[1] + c[1])};
}

// ---------------- fused setup: all W1/W2 transposes + pred_init ----------------
struct SetupArgs {
    const float* W1s[3]; __hip_bfloat16* W1T[3]; int K[3];
    const float* W2s[3]; __hip_bfloat16* W2T[3];
    const float* lf; const float* Wt; const float* bt; float* pred;
};

__device__ inline void transpose_tile(const float* __restrict__ src,
                                      __hip_bfloat16* __restrict__ dst,
                                      int R, int C, int rowT, int colT,
                                      float (*tile)[33]) {
    int tx = threadIdx.x & 31, ty = threadIdx.x >> 5;  // 32 x 8
    int r0 = rowT * 32, c0 = colT * 32;
    #pragma unroll
    for (int k = 0; k < 4; ++k)
        tile[ty + k * 8][tx] = src[(size_t)(r0 + ty + k * 8) * C + c0 + tx];
    __syncthreads();
    #pragma unroll
    for (int k = 0; k < 4; ++k)
        dst[(size_t)(c0 + ty + k * 8) * R + r0 + tx] =
            __float2bfloat16(tile[tx][ty + k * 8]);
}

// grid: [0,43904) W1 tiles | [43904,44672) W2 tiles | [44672,44816) pred
__global__ __launch_bounds__(256) void setup_kernel(SetupArgs a) {
    __shared__ float tile[32][33];
    int id = blockIdx.x;
    if (id < 43904) {
        int h = (id < 25088) ? 0 : (id < 37632 ? 1 : 2);
        int base = (h == 0) ? 0 : (h == 1 ? 25088 : 37632);
        int l = id - base;
        transpose_tile(a.W1s[h], a.W1T[h], a.K[h], 1024, l >> 5, l & 31, tile);
    } else if (id < 44672) {
        int l = id - 43904;
        int h = l >> 8; int t = l & 255;
        transpose_tile(a.W2s[h], a.W2T[h], 1024, 256, t >> 3, t & 7, tile);
    } else {
        int l = id - 44672;
        int wave = threadIdx.x >> 6, lane = threadIdx.x & 63;
        int task = l * 4 + wave;         // < 576 = 32*18
        int j = task % 18, b = task / 18;
        const float* lfb = a.lf + (size_t)b * 4096;
        float acc = 0.f;
        for (int k = lane; k < 4096; k += 64)
            acc += lfb[k] * a.Wt[(size_t)k * 18 + j];
        #pragma unroll
        for (int off = 32; off >= 1; off >>= 1)
            acc += __shfl_xor(acc, off, 64);
        if (lane == 0) a.pred[b * 18 + j] = acc + a.bt[j];
    }
}

// ---------------- bilinear ROI sampling (LDS-cached coords, float4) ----------------
// grid.y splits the pixel*channel space for TLP (total4 must divide gridDim.y)
__global__ __launch_bounds__(256) void sample_kernel(
    const float* __restrict__ feat, int Wd, int lc,
    const float* __restrict__ pred0, const float* __restrict__ ptPrev, int nsegP,
    int lns, __hip_bfloat16* __restrict__ x)
{
    int nseg = 1 << lns;
    int blk = blockIdx.x;
    int i = blk & (nseg - 1), b = blk >> lns;
    float2 p0 = pred_point(pred0, ptPrev, nsegP, b, i);
    float2 p1 = pred_point(pred0, ptPrev, nsegP, b, i + 1);
    float cx = 0.5f * (p0.x + p1.x), cy = 0.5f * (p0.y + p1.y);
    float dx = 0.5f * (p1.x - p0.x), dy = 0.5f * (p1.y - p0.y);

    __shared__ float4 wv[49];
    __shared__ int4   ov[49];   // offsets in float4 units
    int t = threadIdx.x;
    int C = 1 << lc;
    if (t < 49) {
        int oy = t / 7, ox = t - oy * 7;
        float gx = (float)(ox - 3) * (1.f / 3.f);
        float gy = (float)(oy - 3) * (1.f / 3.f);
        float xs = dx * gx - dy * gy - cx;
        float ys = dy * gx + dx * gy - cy;
        float fW = (float)(Wd - 1);
        float px = (xs + 1.f) * fW * 0.5f;
        float py = (ys + 1.f) * fW * 0.5f;
        float x0f = floorf(px), y0f = floorf(py);
        float wx = px - x0f, wy = py - y0f;
        int xi0 = (int)fminf(fmaxf(x0f,       0.f), fW);
        int xi1 = (int)fminf(fmaxf(x0f + 1.f, 0.f), fW);
        int yi0 = (int)fminf(fmaxf(y0f,       0.f), fW);
        int yi1 = (int)fminf(fmaxf(y0f + 1.f, 0.f), fW);
        int c4 = C >> 2;
        ov[t] = int4{(yi0 * Wd + xi0) * c4, (yi1 * Wd + xi0) * c4,
                     (yi0 * Wd + xi1) * c4, (yi1 * Wd + xi1) * c4};
        wv[t] = float4{(1.f - wx) * (1.f - wy), (1.f - wx) * wy,
                       wx * (1.f - wy),         wx * wy};
    }
    __syncthreads();

    const float4* fb4 = (const float4*)(feat + (size_t)b * Wd * Wd * C);
    int c4 = 1 << (lc - 2);
    int total4 = 49 << (lc - 2);
    int chunk = total4 / gridDim.y;
    int j0 = blockIdx.y * chunk;
    size_t rowbase = (size_t)blk * (49 << lc);
    for (int j = j0 + t; j < j0 + chunk; j += 256) {
        int pix = j >> (lc - 2);
        int cc  = j & (c4 - 1);
        int4 o = ov[pix]; float4 w = wv[pix];
        float4 Ia = fb4[o.x + cc], Ib = fb4[o.y + cc];
        float4 Ic = fb4[o.z + cc], Id = fb4[o.w + cc];
        float4 v;
        v.x = w.x * Ia.x + w.y * Ib.x + w.z * Ic.x + w.w * Id.x;
        v.y = w.x * Ia.y + w.y * Ib.y + w.z * Ic.y + w.w * Id.y;
        v.z = w.x * Ia.z + w.y * Ib.z + w.z * Ic.z + w.w * Id.z;
        v.w = w.x * Ia.w + w.y * Ib.w + w.z * Ic.w + w.w * Id.w;
        __hip_bfloat16 h0 = __float2bfloat16(v.x), h1 = __float2bfloat16(v.y);
        __hip_bfloat16 h2 = __float2bfloat16(v.z), h3 = __float2bfloat16(v.w);
        ushort4 u = {*(unsigned short*)&h0, *(unsigned short*)&h1,
                     *(unsigned short*)&h2, *(unsigned short*)&h3};
        *(ushort4*)(x + rowbase + ((size_t)pix << lc) + cc * 4) = u;
    }
}

// ---------------- bf16 MFMA GEMM, split-K, 4 waves/block sharing A ----------------
// A: (M,K) bf16 row-major. Bt: (N,K) bf16 row-major. P: (S,M,N) fp32 partials.
// grid = (M/64, N/256, S); block = 256 (4 waves). wave w covers n-tile ntb*4+w.
// Depth-2 rotating prefetch: MM(chunk c) waits only for loads issued 2 chunks back.
__global__ __launch_bounds__(256) void gemm_mfma4(
    const __hip_bfloat16* __restrict__ A, const __hip_bfloat16* __restrict__ Bt,
    float* __restrict__ P, int M, int N, int K, int slice)
{
    int lane = threadIdx.x & 63;
    int wave = threadIdx.x >> 6;
    int lo = lane & 15, hi = lane >> 4;
    int mt = blockIdx.x, nt = blockIdx.y * 4 + wave, s = blockIdx.z;
    const short* Ap = (const short*)A + (size_t)(mt * 64 + lo) * K + (size_t)s * slice + hi * 8;
    const short* Bp = (const short*)Bt + (size_t)(nt * 64 + lo) * K + (size_t)s * slice + hi * 8;

    floatx4 acc[4][4];
    #pragma unroll
    for (int a = 0; a < 4; ++a)
        #pragma unroll
        for (int b = 0; b < 4; ++b)
            acc[a][b] = floatx4{0.f, 0.f, 0.f, 0.f};

    short8 a0[4], b0[4], a1[4], b1[4], a2[4], b2[4];
    int nch = slice >> 5;

#define LDF(da, db, koff)                                                     \
    {                                                                         \
        _Pragma("unroll")                                                     \
        for (int q = 0; q < 4; ++q)                                           \
            da[q] = *(const short8*)(Ap + (size_t)q * 16 * K + (koff));       \
        _Pragma("unroll")                                                     \
        for (int q = 0; q < 4; ++q)                                           \
            db[q] = *(const short8*)(Bp + (size_t)q * 16 * K + (koff));       \
    }
#define MM(da, db)                                                            \
    {                                                                         \
        __builtin_amdgcn_s_setprio(1);                                        \
        _Pragma("unroll")                                                     \
        for (int mi = 0; mi < 4; ++mi)                                        \
            _Pragma("unroll")                                                 \
            for (int ni = 0; ni < 4; ++ni)                                    \
                acc[mi][ni] = __builtin_amdgcn_mfma_f32_16x16x32_bf16(        \
                    da[mi], db[ni], acc[mi][ni], 0, 0, 0);                    \
        __builtin_amdgcn_s_setprio(0);                                        \
    }

    LDF(a0, b0, 0)
    if (nch >= 2) LDF(a1, b1, 32)
    int c = 0;
    for (; c + 5 < nch; c += 3) {
        LDF(a2, b2, (c + 2) * 32)
        MM(a0, b0)
        LDF(a0, b0, (c + 3) * 32)
        MM(a1, b1)
        LDF(a1, b1, (c + 4) * 32)
        MM(a2, b2)
    }
    int r = nch - c;   // 1..5 chunks remain; a0=chunk c, a1=chunk c+1 loaded
    if (r == 1) { MM(a0, b0) }
    else if (r == 2) { MM(a0, b0) MM(a1, b1) }
    else if (r == 3) {
        LDF(a2, b2, (c + 2) * 32)
        MM(a0, b0) MM(a1, b1) MM(a2, b2)
    } else if (r == 4) {
        LDF(a2, b2, (c + 2) * 32)
        MM(a0, b0)
        LDF(a0, b0, (c + 3) * 32)
        MM(a1, b1) MM(a2, b2) MM(a0, b0)
    } else {
        LDF(a2, b2, (c + 2) * 32)
        MM(a0, b0)
        LDF(a0, b0, (c + 3) * 32)
        MM(a1, b1)
        LDF(a1, b1, (c + 4) * 32)
        MM(a2, b2) MM(a0, b0) MM(a1, b1)
    }

    #pragma unroll
    for (int mi = 0; mi < 4; ++mi) {
        int row0 = mt * 64 + mi * 16 + hi * 4;
        #pragma unroll
        for (int ni = 0; ni < 4; ++ni) {
            int col = nt * 64 + ni * 16 + lo;
            #pragma unroll
            for (int r2 = 0; r2 < 4; ++r2)
                P[((size_t)s * M + row0 + r2) * N + col] = acc[mi][ni][r2];
        }
    }
#undef LDF
#undef MM
}

// ---------------- reduce split-K partials + bias + tanh -> bf16 (float4/thread) ----
__global__ __launch_bounds__(256) void reduce_tanh_kernel(
    const float* __restrict__ P1, const float* __restrict__ b1,
    __hip_bfloat16* __restrict__ f1, int M, int S)
{
    size_t e = ((size_t)blockIdx.x * 256 + threadIdx.x) * 4;
    int n = (int)(e & 1023);
    float4 v = *(const float4*)(b1 + n);
    size_t stride = (size_t)M * 1024;
    for (int s = 0; s < S; ++s) {
        float4 p = *(const float4*)(P1 + (size_t)s * stride + e);
        v.x += p.x; v.y += p.y; v.z += p.z; v.w += p.w;
    }
    __hip_bfloat16 h0 = __float2bfloat16(tanhf(v.x));
    __hip_bfloat16 h1 = __float2bfloat16(tanhf(v.y));
    __hip_bfloat16 h2 = __float2bfloat16(tanhf(v.z));
    __hip_bfloat16 h3 = __float2bfloat16(tanhf(v.w));
    ushort4 u = {*(unsigned short*)&h0, *(unsigned short*)&h1,
                 *(unsigned short*)&h2, *(unsigned short*)&h3};
    *(ushort4*)(f1 + e) = u;
}

// ---------------- head: reduce P2 + b2, tanh, @W3+b3+off, theta transform -> pt ----
// 4 rows per block, one wave per row.
__global__ __launch_bounds__(256) void gemm3pts_kernel(
    const float* __restrict__ P2, const float* __restrict__ b2,
    const float* __restrict__ W3, const float* __restrict__ b3,
    const float* __restrict__ pred0, const float* __restrict__ ptPrev, int nsegP,
    float* __restrict__ pt, int lns, int M)
{
    int wave = threadIdx.x >> 6;
    int m = blockIdx.x * 4 + wave;
    int lane = threadIdx.x & 63;
    int nseg = 1 << lns;
    float acc[6] = {0.f, 0.f, 0.f, 0.f, 0.f, 0.f};
    #pragma unroll
    for (int q = 0; q < 4; ++q) {
        int k = lane + q * 64;
        float v = b2[k];
        #pragma unroll
        for (int s = 0; s < 8; ++s)
            v += P2[((size_t)s * M + m) * 256 + k];
        v = tanhf(v);
        const float* w = W3 + (size_t)k * 6;
        #pragma unroll
        for (int j = 0; j < 6; ++j) acc[j] += v * w[j];
    }
    #pragma unroll
    for (int j = 0; j < 6; ++j)
        #pragma unroll
        for (int off = 32; off >= 1; off >>= 1)
            acc[j] += __shfl_xor(acc[j], off, 64);
    if (lane == 0) {
        int i = m & (nseg - 1);
        int b = m >> lns;
        float2 p0 = pred_point(pred0, ptPrev, nsegP, b, i);
        float2 p1 = pred_point(pred0, ptPrev, nsegP, b, i + 1);
        float cx = 0.5f * (p0.x + p1.x), cy = 0.5f * (p0.y + p1.y);
        float dx = 0.5f * (p1.x - p0.x), dy = 0.5f * (p1.y - p0.y);
        float f[6];
        #pragma unroll
        for (int j = 0; j < 6; ++j) f[j] = acc[j] + b3[j];
        f[0] -= 1.f;
        f[4] += 1.f;
        int npnt = nseg * 3;
        size_t base = ((size_t)b * npnt + 3 * i) * 2;
        #pragma unroll
        for (int s = 0; s < 3; ++s) {
            float px = f[2 * s], py = f[2 * s + 1];
            pt[base + 2 * s]     = dx * px - dy * py + cx;
            pt[base + 2 * s + 1] = dy * px + dx * py + cy;
        }
    }
}

// ---------------- final pair gather -> d_out (*6, drop last) ----------------
__global__ __launch_bounds__(256) void pairs_final_kernel(
    const float* __restrict__ pt, float* __restrict__ outp, int nsegP)
{
    int npnt = nsegP * 3;
    int Pn = 2 * nsegP + 1;
    int idx = blockIdx.x * 256 + threadIdx.x;
    int total = 32 * Pn * 2;
    if (idx >= total) return;
    int c = idx & 1;
    int t = idx >> 1;
    int p = t % Pn, b = t / Pn;
    int i1, i2; pair_idx(p, Pn, npnt, i1, i2);
    float v = 0.5f * (pt[((size_t)b * npnt + i1) * 2 + c] +
                      pt[((size_t)b * npnt + i2) * 2 + c]);
    if (p < Pn - 1) outp[((size_t)b * (Pn - 1) + p) * 2 + c] = 6.f * v;
}

// ---------------- launch ----------------
extern "C" void kernel_launch(void* const* d_in, const int* in_sizes, int n_in,
                              void* d_out, int out_size, void* d_ws, size_t ws_size,
                              hipStream_t stream) {
    (void)in_sizes; (void)n_in; (void)out_size; (void)ws_size;
    const float* feats[3] = {(const float*)d_in[1], (const float*)d_in[2], (const float*)d_in[3]};

    char* ws = (char*)d_ws;
    float* predA = (float*)(ws + OFF_PRED);
    float* ptA   = (float*)(ws + OFF_PTA);
    float* ptB   = (float*)(ws + OFF_PTB);
    __hip_bfloat16* f1 = (__hip_bfloat16*)(ws + OFF_F1);
    float* P2          = (float*)(ws + OFF_P2);
    __hip_bfloat16* xb = (__hip_bfloat16*)(ws + OFF_X);
    float* P1          = (float*)(ws + OFF_P1);

    const int Ks[3]  = {25088, 12544, 6272};
    const int S1s[3] = {28, 14, 7};          // slice = 896 everywhere
    const int lcs[3] = {9, 8, 7};
    const int Hs[3]  = {28, 56, 112};
    const int lnss[3] = {3, 4, 5};
    const int nspl[3] = {4, 4, 2};           // sample grid.y split per level

    SetupArgs sa;
    size_t w1off = 0;
    for (int h = 0; h < 3; ++h) {
        sa.W1s[h] = (const float*)d_in[6 + 6 * h];
        sa.W1T[h] = (__hip_bfloat16*)(ws + OFF_W1T + w1off);
        sa.K[h]   = Ks[h];
        w1off += (size_t)Ks[h] * 1024 * 2;
        sa.W2s[h] = (const float*)d_in[8 + 6 * h];
        sa.W2T[h] = (__hip_bfloat16*)(ws + OFF_W2T + (size_t)h * 524288);
    }
    sa.lf = (const float*)d_in[0];
    sa.Wt = (const float*)d_in[4];
    sa.bt = (const float*)d_in[5];
    sa.pred = predA;

    setup_kernel<<<dim3(44816), 256, 0, stream>>>(sa);

    float* pts[2] = {ptA, ptB};
    const float* ptPrev = nullptr;
    int nsegP = 0;
    for (int h = 0; h < 3; ++h) {
        int lns = lnss[h], nseg = 1 << lns, M = 32 * nseg;
        int K = Ks[h], S1 = S1s[h];
        const float* b1 = (const float*)d_in[7 + 6 * h];
        const float* b2 = (const float*)d_in[9 + 6 * h];
        const float* W3 = (const float*)d_in[10 + 6 * h];
        const float* b3 = (const float*)d_in[11 + 6 * h];

        sample_kernel<<<dim3(32 * nseg, nspl[h]), 256, 0, stream>>>(
            feats[h], Hs[h], lcs[h], predA, ptPrev, nsegP, lns, xb);

        gemm_mfma4<<<dim3(M / 64, 4, S1), 256, 0, stream>>>(
            xb, sa.W1T[h], P1, M, 1024, K, K / S1);

        reduce_tanh_kernel<<<dim3(M), 256, 0, stream>>>(P1, b1, f1, M, S1);

        gemm_mfma4<<<dim3(M / 64, 1, 8), 256, 0, stream>>>(
            f1, sa.W2T[h], P2, M, 256, 1024, 128);

        float* ptCur = pts[h & 1];
        gemm3pts_kernel<<<dim3(M / 4), 256, 0, stream>>>(
            P2, b2, W3, b3, predA, ptPrev, nsegP, ptCur, lns, M);

        ptPrev = ptCur; nsegP = nseg;
    }

    pairs_final_kernel<<<dim3((32 * 65 * 2 + 255) / 256), 256, 0, stream>>>(
        ptA, (float*)d_out, 32);
}